// Round 7
// baseline (225.455 us; speedup 1.0000x reference)
//
#include <hip/hip_runtime.h>
#include <hip/hip_bf16.h>
#include <stdint.h>

#define DI __device__ __forceinline__

typedef float f32x4 __attribute__((ext_vector_type(4)));
typedef short bf16x8 __attribute__((ext_vector_type(8)));

constexpr int BATCH = 4;
constexpr int C = 256;       // channels (= d_v)
constexpr int N = 4096;      // H*W
constexpr int NO = 320;      // 32 q + 32 k + 256 v output rows
constexpr int KB2 = 64;      // keys per attention iteration
constexpr int NT2 = N / KB2; // 64 iterations
constexpr float LOG2E = 1.44269504088896340736f;

DI unsigned short f2bf(float f) {
  union { float f; unsigned int i; } v; v.f = f;
  unsigned int r = v.i + 0x7fffu + ((v.i >> 16) & 1u);   // RNE
  return (unsigned short)(r >> 16);
}

DI float exp2i(float x) {  // raw v_exp_f32 (D = 2^S0)
  float r; asm("v_exp_f32 %0, %1" : "=v"(r) : "v"(x)); return r;
}

DI unsigned int cvtpk(float lo, float hi) {  // packed bf16 pair (no builtin, m240)
  unsigned int r;
  asm("v_cvt_pk_bf16_f32 %0, %1, %2" : "=v"(r) : "v"(lo), "v"(hi));
  return r;
}

// ---------------- kernel 0: pack weights/biases to bf16 ----------------
// Wq/bq pre-scaled by log2e so attention scores come out in log2 domain.
__global__ __launch_bounds__(256) void prep_kernel(
    const float* __restrict__ Wq, const float* __restrict__ Wk, const float* __restrict__ Wv,
    const float* __restrict__ bq, const float* __restrict__ bk, const float* __restrict__ bv,
    unsigned short* __restrict__ Wcat, float* __restrict__ bcat) {
  int idx = blockIdx.x * 256 + threadIdx.x;
  if (idx < NO * C) {
    int row = idx >> 8, c = idx & 255;
    float v = (row < 32) ? Wq[row * 256 + c] * LOG2E
            : (row < 64) ? Wk[(row - 32) * 256 + c]
                         : Wv[(row - 64) * 256 + c];
    Wcat[idx] = f2bf(v);
  }
  if (idx < NO) {
    float v = (idx < 32) ? bq[idx] * LOG2E
            : (idx < 64) ? bk[idx - 32] : bv[idx - 64];
    bcat[idx] = v;
  }
}

// ---------------- kernel 1: QKV projection (MFMA, z-split over outputs) ----------------
// out[n,o] = sum_c x[c,n] * Wcat[o,c] + bcat[o]
// z-block handles 4 of 20 o-tiles: z=0 -> q,k ; z=1..4 -> 64 v-rows each.
__global__ __launch_bounds__(256) void proj_kernel(
    const float* __restrict__ x, const unsigned short* __restrict__ Wcat,
    const float* __restrict__ bcat,
    unsigned short* __restrict__ qarr, unsigned short* __restrict__ karr,
    unsigned short* __restrict__ vT) {
  // stride 66 u16 = 33 words: row step 8 -> 264 % 32 = 8 -> gather spreads all banks (2-way)
  __shared__ __align__(16) unsigned short ldsx[C][66];  // 33.8KB

  int b = blockIdx.y, n0 = blockIdx.x * 64, z = blockIdx.z;
  int t = threadIdx.x, lane = t & 63, w = t >> 6;
  int g = lane >> 4, cq = lane & 15;

  // stage x tile [256c][64n] -> bf16 LDS (float4 loads, two b32 LDS writes each)
  const float* xb = x + (size_t)b * C * N;
  {
    int csub = lane >> 4, m = lane & 15;
    #pragma unroll 4
    for (int cc = 0; cc < 16; ++cc) {
      int c = cc * 16 + w * 4 + csub;
      f32x4 v = *(const f32x4*)(xb + (size_t)c * N + n0 + m * 4);
      unsigned int p01 = ((unsigned int)f2bf(v[0])) | ((unsigned int)f2bf(v[1]) << 16);
      unsigned int p23 = ((unsigned int)f2bf(v[2])) | ((unsigned int)f2bf(v[3]) << 16);
      *(unsigned int*)(&ldsx[c][m * 4]) = p01;      // 4B-aligned (c*132 + m*8)
      *(unsigned int*)(&ldsx[c][m * 4 + 2]) = p23;
    }
  }
  __syncthreads();

  // gather A-frags: A[row=n][k=c], lane holds row=w*16+cq, k=(g*8..+7) per 32-k step
  bf16x8 afrag[8];
  int nrow = w * 16 + cq;
  #pragma unroll
  for (int ks = 0; ks < 8; ++ks) {
    bf16x8 a;
    #pragma unroll
    for (int j = 0; j < 8; ++j) a[j] = (short)ldsx[ks * 32 + g * 8 + j][nrow];
    afrag[ks] = a;
  }
  __syncthreads();  // done reading ldsx; reuse as v-transpose buffer

  unsigned short (*vlds)[66] = (unsigned short (*)[66]) & ldsx[0][0];  // [64n][66]

  #pragma unroll
  for (int i = 0; i < 4; ++i) {
    int oc = z * 4 + i;
    int o = oc * 16 + cq;
    f32x4 acc = {0.f, 0.f, 0.f, 0.f};
    const unsigned short* wrow = Wcat + o * 256;  // B[k=c][col=o], 16B contig
    #pragma unroll
    for (int ks = 0; ks < 8; ++ks) {
      bf16x8 bf = *(const bf16x8*)(wrow + ks * 32 + g * 8);
      acc = __builtin_amdgcn_mfma_f32_16x16x32_bf16(afrag[ks], bf, acc, 0, 0, 0);
    }
    float bias = bcat[o];
    // D: row(local n) = g*4+r, col = o
    if (z == 0) {
      unsigned short* dst = (oc < 2) ? qarr : karr;
      int od = ((oc & 1) << 4) + cq;
      #pragma unroll
      for (int r = 0; r < 4; ++r) {
        int n = n0 + w * 16 + g * 4 + r;
        dst[((size_t)b * N + n) * 32 + od] = f2bf(acc[r] + bias);
      }
    } else {
      int el = i * 16 + cq;  // e-local 0..63
      #pragma unroll
      for (int r = 0; r < 4; ++r)
        vlds[w * 16 + g * 4 + r][el] = f2bf(acc[r] + bias);
    }
  }

  if (z > 0) {
    __syncthreads();
    int e0 = (z - 1) * 64;
    // coalesced vT write: lane = n column, wave strides over e-local rows
    #pragma unroll 4
    for (int ep = 0; ep < 16; ++ep) {
      int el = ep * 4 + w;
      vT[((size_t)b * 256 + e0 + el) * N + n0 + lane] = vlds[lane][el];
    }
  }
}

// ---------------- kernel 2: attention (512 blocks, e-half split, statless) ----------------
// Block = (batch, 64-q tile, e-half of 128). 8 waves. Score: wave w -> q-tile (w&3),
// key-half (w>>2), keys interleaved even/odd so cvt_pk writes land in natural key order.
// PV: wave w owns e in [eh*128 + w*16, +16). p = 2^(s' - 20*log2e) (Q pre-scaled),
// L via ones-row MFMA (waves 0-3). 2 blocks/CU -> 4 waves/SIMD.
__global__ __launch_bounds__(512) void attn_kernel(
    const unsigned short* __restrict__ qarr, const unsigned short* __restrict__ karr,
    const unsigned short* __restrict__ vT, const float* __restrict__ x,
    const float* __restrict__ gamma_p, float* __restrict__ out) {
  // P: [buf][64 q][36 u32] (row = 64 keys bf16 + pad). Row stride 144B:
  // b32 writes -> bank (4row + kh*16 + cq)%32 = 2 lanes/bank (free);
  // b128 reads -> 8 lanes per 4-bank window (optimal for b128).
  __shared__ __align__(16) unsigned int plds[2][64][36];  // 18.4 KB
  __shared__ float lsc[64];

  int bid = blockIdx.x;
  // bijective: xcd = bid&7 -> batch pair; per batch, K/Q/V L2-resident on 2 XCDs
  int xcd = bid & 7;
  int b = xcd >> 1;
  int eh = (bid >> 3) & 1;
  int tile = ((bid >> 4) << 1) | (bid & 1);  // 0..63

  int t = threadIdx.x, lane = t & 63, w = t >> 6;
  int g = lane >> 4, cq = lane & 15;
  int qw = w & 3, kh = w >> 2;

  const unsigned short* kb = karr + (size_t)b * N * 32;
  const unsigned short* vTb = vT + (size_t)b * C * N;

  // Q A-frag: A[row=q=cq][k=d=g*8..+7]
  bf16x8 qf = *(const bf16x8*)(qarr + ((size_t)b * N + tile * 64 + qw * 16 + cq) * 32 + g * 8);

  // ones A-frag: row 0 = 1.0 -> D row0 = col-sum of B
  short onev = (cq == 0) ? (short)0x3F80 : (short)0;
  bf16x8 onesA = {onev, onev, onev, onev, onev, onev, onev, onev};

  f32x4 o[4];   // [qc]: D row = e-local g*4+r, col = q = cq
  #pragma unroll
  for (int j = 0; j < 4; ++j) o[j] = f32x4{0.f, 0.f, 0.f, 0.f};
  f32x4 oL = {0.f, 0.f, 0.f, 0.f};

  // V A-frag: e = eh*128 + w*16 + cq (row = lane&15), k-chunk g*8 (+32 for s=1)
  const unsigned short* vbase = vTb + (size_t)(eh * 128 + w * 16 + cq) * N + g * 8;
  // K B-frags with even/odd interleave: col cq <-> keys kh*32 + 2cq, 2cq+1
  const unsigned short* kbase0 = kb + (size_t)(kh * 32 + 2 * cq) * 32 + g * 8;

  // prologue: iter-0 operands
  bf16x8 kf0 = *(const bf16x8*)(kbase0);
  bf16x8 kf1 = *(const bf16x8*)(kbase0 + 32);
  bf16x8 vf0 = *(const bf16x8*)(vbase);
  bf16x8 vf1 = *(const bf16x8*)(vbase + 32);

  const float C2 = 20.0f * LOG2E;  // shift in log2 domain

  for (int nt = 0; nt < NT2; ++nt) {
    int pb = nt & 1;
    int nn2 = ((nt + 1) & (NT2 - 1)) * KB2;  // next tile, wrapped

    // prefetch next-iter K and V (full iteration of latency to land)
    bf16x8 nk0 = *(const bf16x8*)(kbase0 + (size_t)nn2 * 32);
    bf16x8 nk1 = *(const bf16x8*)(kbase0 + (size_t)nn2 * 32 + 32);
    bf16x8 nv0 = *(const bf16x8*)(vbase + nn2);
    bf16x8 nv1 = *(const bf16x8*)(vbase + nn2 + 32);

    // scores (log2 domain): D[row=q=g*4+r][col=cq] ; col cq = keys 2cq / 2cq+1
    f32x4 s0 = __builtin_amdgcn_mfma_f32_16x16x32_bf16(qf, kf0, f32x4{0.f,0.f,0.f,0.f}, 0, 0, 0);
    f32x4 s1 = __builtin_amdgcn_mfma_f32_16x16x32_bf16(qf, kf1, f32x4{0.f,0.f,0.f,0.f}, 0, 0, 0);

    // p = 2^(s - C2); pack pair -> one b32 store in natural key order
    #pragma unroll
    for (int r = 0; r < 4; ++r) {
      float p0 = exp2i(s0[r] - C2);
      float p1 = exp2i(s1[r] - C2);
      plds[pb][qw * 16 + g * 4 + r][kh * 16 + cq] = cvtpk(p0, p1);
    }

    // make P visible WITHOUT draining vmcnt (K/V prefetch stays in flight)
    asm volatile("s_waitcnt lgkmcnt(0)\n\ts_barrier" ::: "memory");

    // PV: O^T[e][q] += V^T[e][n] * P^T[n][q]; L via ones-row (waves 0-3)
    __builtin_amdgcn_s_setprio(1);
    #pragma unroll
    for (int qc = 0; qc < 4; ++qc) {
      const unsigned short* prow = (const unsigned short*)&plds[pb][qc * 16 + cq][0];
      bf16x8 pf0 = *(const bf16x8*)(prow + g * 8);        // keys 0..31 slot
      bf16x8 pf1 = *(const bf16x8*)(prow + 32 + g * 8);   // keys 32..63 slot
      o[qc] = __builtin_amdgcn_mfma_f32_16x16x32_bf16(vf0, pf0, o[qc], 0, 0, 0);
      o[qc] = __builtin_amdgcn_mfma_f32_16x16x32_bf16(vf1, pf1, o[qc], 0, 0, 0);
      if (qc == w) {  // wave-uniform; only waves 0-3 match
        oL = __builtin_amdgcn_mfma_f32_16x16x32_bf16(onesA, pf0, oL, 0, 0, 0);
        oL = __builtin_amdgcn_mfma_f32_16x16x32_bf16(onesA, pf1, oL, 0, 0, 0);
      }
    }
    __builtin_amdgcn_s_setprio(0);

    kf0 = nk0; kf1 = nk1; vf0 = nv0; vf1 = nv1;
  }

  // L: wave w<4 holds L[w*16+cq] in lanes 0..15 (g=0), reg 0
  if (w < 4 && lane < 16) lsc[w * 16 + lane] = gamma_p[0] / oL[0];
  __syncthreads();

  // epilogue: out[b][e][q] = scale[q] * O^T[e][q] + x[b][e][q]
  const float* xb = x + (size_t)b * C * N;
  float* ob = out + (size_t)b * C * N;
  #pragma unroll
  for (int qc = 0; qc < 4; ++qc) {
    float scale = lsc[qc * 16 + cq];
    int qg = tile * 64 + qc * 16 + cq;
    #pragma unroll
    for (int r = 0; r < 4; ++r) {
      int e = eh * 128 + w * 16 + g * 4 + r;
      size_t idx = (size_t)e * N + qg;
      ob[idx] = o[qc][r] * scale + xb[idx];
    }
  }
}

// ---------------- launch ----------------
extern "C" void kernel_launch(void* const* d_in, const int* in_sizes, int n_in,
                              void* d_out, int out_size, void* d_ws, size_t ws_size,
                              hipStream_t stream) {
  const float* x  = (const float*)d_in[0];
  const float* Wq = (const float*)d_in[1];
  const float* bq = (const float*)d_in[2];
  const float* Wk = (const float*)d_in[3];
  const float* bk = (const float*)d_in[4];
  const float* Wv = (const float*)d_in[5];
  const float* bv = (const float*)d_in[6];
  const float* gamma = (const float*)d_in[7];
  float* out = (float*)d_out;

  char* ws = (char*)d_ws;
  unsigned short* Wcat = (unsigned short*)(ws);               // 320*256*2 = 163840
  float* bcat          = (float*)(ws + 163840);               // 320*4     = 1280
  unsigned short* qarr = (unsigned short*)(ws + 165120);      // 4*4096*32*2 = 1048576
  unsigned short* karr = (unsigned short*)(ws + 1213696);     // 1048576
  unsigned short* vT   = (unsigned short*)(ws + 2262272);     // 4*256*4096*2 = 8388608
  // total ws use: 10,650,880 bytes

  prep_kernel<<<320, 256, 0, stream>>>(Wq, Wk, Wv, bq, bk, bv, Wcat, bcat);
  proj_kernel<<<dim3(64, 4, 5), 256, 0, stream>>>(x, Wcat, bcat, qarr, karr, vT);
  attn_kernel<<<512, 512, 0, stream>>>(qarr, karr, vT, x, gamma, out);
}